// Round 7
// baseline (465.941 us; speedup 1.0000x reference)
//
#include <hip/hip_runtime.h>
#include <hip/hip_bf16.h>

#define NN 50000          // nodes
#define NE 800000         // edges
#define NR 3              // relations
#define NG 500            // graphs
#define NB (NN * NR)      // (dst, rel) buckets = 150000
#define NCLS 10
#define NCMB 8192         // 8 shapes * 8 colors * 128 positions
#define CHUNK 2048        // scan elements per block
#define NBLK ((NB + CHUNK - 1) / CHUNK)   // 74

typedef __hip_bfloat16 bf16;
typedef __attribute__((ext_vector_type(8))) short short8;   // bf16x8 MFMA frag
typedef __attribute__((ext_vector_type(4))) float floatx4;  // MFMA accumulator

static __device__ __forceinline__ float b2f(bf16 x) { return __bfloat162float(x); }
static __device__ __forceinline__ bf16  f2b(float x) { return __float2bfloat16(x); }
static __device__ __forceinline__ float bs2f(short x) {
    return __bfloat162float(*reinterpret_cast<const bf16*>(&x));
}
static __device__ __forceinline__ short f2bs(float x) {
    bf16 b = __float2bfloat16(x);
    return *reinterpret_cast<const short*>(&b);
}

// ---------------- zero words (graph-capture-safe)
__global__ __launch_bounds__(256) void zero_u32(unsigned* __restrict__ p, long n) {
    long i = (long)blockIdx.x * 256 + threadIdx.x;
    if (i < n) p[i] = 0u;
}

// ---------------- per-(dst,rel) edge counts
__global__ __launch_bounds__(256) void count_edges(const int* __restrict__ ei,
                                                   const int* __restrict__ et,
                                                   int* __restrict__ cnt) {
    int e = blockIdx.x * 256 + threadIdx.x;
    if (e >= NE) return;
    atomicAdd(&cnt[ei[NE + e] * NR + et[e]], 1);
}

// ---------------- counting-sort scan, phase A: per-block (2048-elem) totals
__global__ __launch_bounds__(256) void scan_block_sums(const int* __restrict__ cnt,
                                                       int* __restrict__ bsum) {
    __shared__ int sm[256];
    int b = blockIdx.x, t = threadIdx.x;
    int base = b * CHUNK + t * 8, s = 0;
#pragma unroll
    for (int j = 0; j < 8; ++j) { int i = base + j; if (i < NB) s += cnt[i]; }
    sm[t] = s; __syncthreads();
    for (int st = 128; st; st >>= 1) { if (t < st) sm[t] += sm[t + st]; __syncthreads(); }
    if (!t) bsum[b] = sm[0];
}

// ---------------- phase B: exclusive scan of the 74 block sums
__global__ void scan_base(const int* __restrict__ bsum, int* __restrict__ bbase,
                          int* __restrict__ off) {
    if (threadIdx.x == 0 && blockIdx.x == 0) {
        int run = 0;
        for (int i = 0; i < NBLK; ++i) { bbase[i] = run; run += bsum[i]; }
        off[NB] = run;   // == NE
    }
}

// ---------------- phase C: in-block exclusive scan + base -> off[], cursor[]
__global__ __launch_bounds__(256) void scan_write(const int* __restrict__ cnt,
                                                  const int* __restrict__ bbase,
                                                  int* __restrict__ off,
                                                  int* __restrict__ cursor) {
    int b = blockIdx.x, t = threadIdx.x;
    int base = b * CHUNK + t * 8;
    int v[8], ts = 0;
#pragma unroll
    for (int j = 0; j < 8; ++j) { int i = base + j; v[j] = (i < NB) ? cnt[i] : 0; ts += v[j]; }
    int lane = t & 63, wv = t >> 6;
    int incl = ts;
    for (int d = 1; d < 64; d <<= 1) {
        int o = __shfl_up(incl, d, 64);
        if (lane >= d) incl += o;
    }
    __shared__ int wsum[4];
    if (lane == 63) wsum[wv] = incl;
    __syncthreads();
    int wbase = 0;
    for (int w = 0; w < wv; ++w) wbase += wsum[w];
    int run = bbase[b] + wbase + incl - ts;
#pragma unroll
    for (int j = 0; j < 8; ++j) {
        int i = base + j;
        if (i < NB) { off[i] = run; cursor[i] = run; }
        run += v[j];
    }
}

// ---------------- bucket-sort edge src indices (CSR payload)
__global__ __launch_bounds__(256) void scatter_edges(const int* __restrict__ ei,
                                                     const int* __restrict__ et,
                                                     int* __restrict__ cursor,
                                                     int* __restrict__ eidx) {
    int e = blockIdx.x * 256 + threadIdx.x;
    if (e >= NE) return;
    int b = ei[NE + e] * NR + et[e];
    int pos = atomicAdd(&cursor[b], 1);
    eidx[pos] = ei[e];
}

// ---------------- layer-1 tables: tab[r][row][n], r in 0..3 (3 rels + root)
__global__ __launch_bounds__(256) void tab_gemm(const float* __restrict__ se,
                                                const float* __restrict__ ce,
                                                const float* __restrict__ pe,
                                                const float* __restrict__ W1,
                                                const float* __restrict__ root1,
                                                float* __restrict__ tab) {
    int bid = blockIdx.x;              // 4*144 blocks
    int r = bid / 144, row = bid % 144;
    int t = threadIdx.x;               // output column 0..255
    const float* A; int segk;
    if (row < 8)       { A = se + row * 128;        segk = 0; }
    else if (row < 16) { A = ce + (row - 8) * 128;  segk = 128; }
    else               { A = pe + (row - 16) * 128; segk = 256; }
    const float* W = (r < 3) ? (W1 + (size_t)r * 384 * 256) : root1;
    float acc = 0.f;
    for (int k = 0; k < 128; ++k)
        acc += A[k] * W[(size_t)(segk + k) * 256 + t];
    tab[((size_t)r * 144 + row) * 256 + t] = acc;
}

// ---------------- node combo ids: combo[n] = s*1024 + c*128 + p
__global__ __launch_bounds__(256) void node_combo(const int* __restrict__ s,
                                                  const int* __restrict__ c,
                                                  const int* __restrict__ p,
                                                  int* __restrict__ combo) {
    int n = blockIdx.x * 256 + threadIdx.x;
    if (n < NN) combo[n] = (s[n] << 10) | (c[n] << 7) | p[n];
}

// ---------------- comb[r][cmb][d] = tab[r][s]+tab[r][8+c]+tab[r][16+p] (+b1 for r=3), bf16
__global__ __launch_bounds__(256) void comb_build(const float* __restrict__ tab,
                                                  const float* __restrict__ b1,
                                                  bf16* __restrict__ comb) {
    int bid = blockIdx.x;              // 4*8192
    int r = bid >> 13, cmb = bid & (NCMB - 1);
    int d = threadIdx.x;
    int si = cmb >> 10, ci = (cmb >> 7) & 7, pi = cmb & 127;
    const float* tr = tab + (size_t)r * 144 * 256;
    float v = tr[si * 256 + d] + tr[(8 + ci) * 256 + d] + tr[(16 + pi) * 256 + d];
    if (r == 3) v += b1[d];
    comb[(size_t)bid * 256 + d] = f2b(v);
}

// ---------------- fused layer 1: 4 waves/block, 1 wave per dst, short4/lane, 4-deep gather
__global__ __launch_bounds__(256) void l1_fused(const int* __restrict__ off,
                                                const int* __restrict__ eidx,
                                                const int* __restrict__ combo,
                                                const bf16* __restrict__ comb,
                                                bf16* __restrict__ h1) {
    int wave = threadIdx.x >> 6, lane = threadIdx.x & 63;
    int dst = blockIdx.x * 4 + wave;
    if (dst >= NN) return;
    int li4 = lane * 4;
    float ax, ay, az, aw;
    {   // root slice (b1 pre-folded)
        int cmbD = combo[dst];
        short4 rv = *(const short4*)(comb + ((size_t)(3 * NCMB) + cmbD) * 256 + li4);
        ax = bs2f(rv.x); ay = bs2f(rv.y); az = bs2f(rv.z); aw = bs2f(rv.w);
    }
    for (int r = 0; r < NR; ++r) {
        int lo = off[dst * NR + r], hi = off[dst * NR + r + 1];
        if (hi <= lo) continue;                 // empty bucket contributes 0 (matches ref)
        const bf16* cr = comb + (size_t)r * NCMB * 256;
        float sx = 0.f, sy = 0.f, sz = 0.f, sw = 0.f;
        int j = lo;
        for (; j + 4 <= hi; j += 4) {           // 4 independent row loads in flight
            int s0 = eidx[j], s1 = eidx[j + 1], s2 = eidx[j + 2], s3 = eidx[j + 3];
            int c0 = combo[s0], c1 = combo[s1], c2 = combo[s2], c3 = combo[s3];
            short4 v0 = *(const short4*)(cr + (size_t)c0 * 256 + li4);
            short4 v1 = *(const short4*)(cr + (size_t)c1 * 256 + li4);
            short4 v2 = *(const short4*)(cr + (size_t)c2 * 256 + li4);
            short4 v3 = *(const short4*)(cr + (size_t)c3 * 256 + li4);
            sx += bs2f(v0.x) + bs2f(v1.x) + bs2f(v2.x) + bs2f(v3.x);
            sy += bs2f(v0.y) + bs2f(v1.y) + bs2f(v2.y) + bs2f(v3.y);
            sz += bs2f(v0.z) + bs2f(v1.z) + bs2f(v2.z) + bs2f(v3.z);
            sw += bs2f(v0.w) + bs2f(v1.w) + bs2f(v2.w) + bs2f(v3.w);
        }
        for (; j < hi; ++j) {
            int cc = combo[eidx[j]];
            short4 v = *(const short4*)(cr + (size_t)cc * 256 + li4);
            sx += bs2f(v.x); sy += bs2f(v.y); sz += bs2f(v.z); sw += bs2f(v.w);
        }
        float inv = 1.0f / (float)(hi - lo);
        ax += sx * inv; ay += sy * inv; az += sz * inv; aw += sw * inv;
    }
    short4 o;
    o.x = f2bs(fmaxf(ax, 0.f)); o.y = f2bs(fmaxf(ay, 0.f));
    o.z = f2bs(fmaxf(az, 0.f)); o.w = f2bs(fmaxf(aw, 0.f));
    *(short4*)(h1 + (size_t)dst * 256 + li4) = o;
}

// ---------------- per-relation mean aggregation of h1 (aggregate BEFORE transform):
// hagg[dst][r*256+d] = mean_{src in bucket(dst,r)} h1[src][d]   (0 if empty)
// 4 waves/block, 1 wave per dst; gathers from L3-hot 25.6 MB h1.
__global__ __launch_bounds__(256) void agg_all(const int* __restrict__ off,
                                               const int* __restrict__ eidx,
                                               const bf16* __restrict__ h1,
                                               bf16* __restrict__ hagg) {
    int wave = threadIdx.x >> 6, lane = threadIdx.x & 63;
    int dst = blockIdx.x * 4 + wave;
    if (dst >= NN) return;
    int li4 = lane * 4;
    for (int r = 0; r < NR; ++r) {
        int lo = off[dst * NR + r], hi = off[dst * NR + r + 1];
        short4 o4 = {0, 0, 0, 0};
        if (hi > lo) {
            float sx = 0.f, sy = 0.f, sz = 0.f, sw = 0.f;
            int j = lo;
            for (; j + 4 <= hi; j += 4) {
                int s0 = eidx[j], s1 = eidx[j + 1], s2 = eidx[j + 2], s3 = eidx[j + 3];
                short4 v0 = *(const short4*)(h1 + (size_t)s0 * 256 + li4);
                short4 v1 = *(const short4*)(h1 + (size_t)s1 * 256 + li4);
                short4 v2 = *(const short4*)(h1 + (size_t)s2 * 256 + li4);
                short4 v3 = *(const short4*)(h1 + (size_t)s3 * 256 + li4);
                sx += bs2f(v0.x) + bs2f(v1.x) + bs2f(v2.x) + bs2f(v3.x);
                sy += bs2f(v0.y) + bs2f(v1.y) + bs2f(v2.y) + bs2f(v3.y);
                sz += bs2f(v0.z) + bs2f(v1.z) + bs2f(v2.z) + bs2f(v3.z);
                sw += bs2f(v0.w) + bs2f(v1.w) + bs2f(v2.w) + bs2f(v3.w);
            }
            for (; j < hi; ++j) {
                short4 v = *(const short4*)(h1 + (size_t)eidx[j] * 256 + li4);
                sx += bs2f(v.x); sy += bs2f(v.y); sz += bs2f(v.z); sw += bs2f(v.w);
            }
            float inv = 1.0f / (float)(hi - lo);
            o4.x = f2bs(sx * inv); o4.y = f2bs(sy * inv);
            o4.z = f2bs(sz * inv); o4.w = f2bs(sw * inv);
        }
        *(short4*)(hagg + (size_t)dst * 768 + r * 256 + li4) = o4;
    }
}

// ---------------- W2cat -> bf16, transposed on K: Wt[n][k], k = [W2_0;W2_1;W2_2;root2]
__global__ __launch_bounds__(256) void conv_w2cat(const float* __restrict__ W2,
                                                  const float* __restrict__ root2,
                                                  bf16* __restrict__ Wt) {
    int idx = blockIdx.x * 256 + threadIdx.x;   // 256*1024
    if (idx >= 256 * 1024) return;
    int n = idx >> 10, k = idx & 1023;
    float v = (k < 768) ? W2[((size_t)(k >> 8) * 256 + (k & 255)) * 256 + n]
                        : root2[(size_t)(k - 768) * 256 + n];
    Wt[idx] = f2b(v);
}

// ---------------- concat MFMA GEMM + fused epilogue:
// h2[M][256] = relu( [hagg | h1] (M x 1024) @ Wt^T + b2 )
// 128x128 tile, 4 waves, each a 64x64 quadrant = 4x4 grid of 16x16x32 MFMAs.
__global__ __launch_bounds__(256) void gemm_cat(const bf16* __restrict__ hagg,
                                                const bf16* __restrict__ h1,
                                                const bf16* __restrict__ Wt,
                                                const float* __restrict__ bias,
                                                bf16* __restrict__ h2) {
    __shared__ short As[128 * 40];   // stride 40 shorts = 80 B (16B-aligned rows)
    __shared__ short Bs[128 * 40];
    const int t = threadIdx.x;
    const int wave = t >> 6, lane = t & 63;
    const int quad = lane >> 4, l16 = lane & 15;
    const int mq = (wave & 1) * 64, nq = (wave >> 1) * 64;
    const int row0 = blockIdx.y * 128, col0 = blockIdx.x * 128;
    const int sm = t >> 2;            // staging row 0..63
    const int sp = (t & 3) * 8;       // staging k-offset {0,8,16,24}

    floatx4 acc[4][4] = {};

    for (int k0 = 0; k0 < 1024; k0 += 32) {
        int k = k0 + sp;              // 768 % 32 == 0: each short8 is single-source
#pragma unroll
        for (int h = 0; h < 2; ++h) {
            int m = sm + h * 64;
            int gm = row0 + m;
            short8 av = {};
            if (gm < NN)
                av = (k < 768) ? *(const short8*)(hagg + (size_t)gm * 768 + k)
                               : *(const short8*)(h1 + (size_t)gm * 256 + (k - 768));
            *(short8*)&As[m * 40 + sp] = av;
            short8 bv = *(const short8*)(Wt + (size_t)(col0 + m) * 1024 + k);
            *(short8*)&Bs[m * 40 + sp] = bv;
        }
        __syncthreads();
        short8 af[4], bfr[4];
#pragma unroll
        for (int i = 0; i < 4; ++i)
            af[i] = *(const short8*)&As[(mq + i * 16 + l16) * 40 + quad * 8];
#pragma unroll
        for (int i = 0; i < 4; ++i)
            bfr[i] = *(const short8*)&Bs[(nq + i * 16 + l16) * 40 + quad * 8];
#pragma unroll
        for (int mi = 0; mi < 4; ++mi)
#pragma unroll
            for (int ni = 0; ni < 4; ++ni)
                acc[mi][ni] = __builtin_amdgcn_mfma_f32_16x16x32_bf16(
                    af[mi], bfr[ni], acc[mi][ni], 0, 0, 0);
        __syncthreads();
    }

    // C/D layout: col = lane&15, row = quad*4 + reg   [m89/m91-verified]
#pragma unroll
    for (int mi = 0; mi < 4; ++mi) {
#pragma unroll
        for (int ni = 0; ni < 4; ++ni) {
            int n = col0 + nq + ni * 16 + l16;
#pragma unroll
            for (int i = 0; i < 4; ++i) {
                int gm = row0 + mq + mi * 16 + quad * 4 + i;
                if (gm < NN) {
                    float v = acc[mi][ni][i] + bias[n];
                    h2[(size_t)gm * 256 + n] = f2b(fmaxf(v, 0.f));
                }
            }
        }
    }
}

// ---------------- pooling via run-length reduction (batch is SORTED)
#define PN 64
__global__ __launch_bounds__(256) void pool_rle(const int* __restrict__ batch,
                                                const bf16* __restrict__ H,
                                                float* __restrict__ pool,
                                                float* __restrict__ gcnt) {
    int t = threadIdx.x;               // feature dim
    int n0 = blockIdx.x * PN;
    int nend = n0 + PN; if (nend > NN) nend = NN;
    int curg = batch[n0];
    float acc = 0.f, cnt = 0.f;
    for (int n = n0; n < nend; ++n) {
        int g = batch[n];              // wave-uniform
        if (g != curg) {
            atomicAdd(&pool[(size_t)curg * 256 + t], acc);
            if (t == 0) atomicAdd(&gcnt[curg], cnt);
            acc = 0.f; cnt = 0.f; curg = g;
        }
        acc += b2f(H[(size_t)n * 256 + t]);
        cnt += 1.f;
    }
    atomicAdd(&pool[(size_t)curg * 256 + t], acc);
    if (t == 0) atomicAdd(&gcnt[curg], cnt);
}

// ---------------- head: out[g][c] = (pool[g]/cnt[g]) @ lin_w + lin_b  (f32 out)
__global__ __launch_bounds__(256) void final_head(const float* __restrict__ pool,
                                                  const float* __restrict__ gcnt,
                                                  const float* __restrict__ lin_w,
                                                  const float* __restrict__ lin_b,
                                                  float* __restrict__ out) {
    __shared__ float sm[256];
    int g = blockIdx.x, t = threadIdx.x;
    float inv = 1.0f / fmaxf(gcnt[g], 1.0f);
    sm[t] = pool[(size_t)g * 256 + t] * inv;
    __syncthreads();
    if (t < NCLS) {
        float s = lin_b[t];
        for (int d = 0; d < 256; ++d) s += sm[d] * lin_w[d * NCLS + t];
        out[g * NCLS + t] = s;
    }
}

extern "C" void kernel_launch(void* const* d_in, const int* in_sizes, int n_in,
                              void* d_out, int out_size, void* d_ws, size_t ws_size,
                              hipStream_t stream) {
    const int*   s_idx = (const int*)d_in[0];
    const int*   c_idx = (const int*)d_in[1];
    const int*   p_idx = (const int*)d_in[2];
    const int*   ei    = (const int*)d_in[3];   // (2, NE)
    const int*   et    = (const int*)d_in[4];
    const int*   batch = (const int*)d_in[5];
    const float* se    = (const float*)d_in[6];
    const float* ce    = (const float*)d_in[7];
    const float* pe    = (const float*)d_in[8];
    const float* W1    = (const float*)d_in[9];   // (3, 384, 256)
    const float* root1 = (const float*)d_in[10];  // (384, 256)
    const float* b1    = (const float*)d_in[11];
    const float* W2    = (const float*)d_in[12];  // (3, 256, 256)
    const float* root2 = (const float*)d_in[13];  // (256, 256)
    const float* b2    = (const float*)d_in[14];
    const float* lin_w = (const float*)d_in[15];
    const float* lin_b = (const float*)d_in[16];
    float* out = (float*)d_out;

    // ---- workspace carve-up (~172 MB; ws_size >= 190 MB confirmed by round-6 wide run)
    char* w = (char*)d_ws;
    size_t o = 0;
    auto alloc = [&](size_t bytes) -> void* {
        o = (o + 15) & ~(size_t)15;
        void* ptr = w + o;
        o += bytes;
        return ptr;
    };
    bf16*  hagg   = (bf16*) alloc((size_t)NN * 768 * 2);   // 76.8 MB
    bf16*  h1     = (bf16*) alloc((size_t)NN * 256 * 2);
    bf16*  h2     = (bf16*) alloc((size_t)NN * 256 * 2);
    bf16*  comb   = (bf16*) alloc((size_t)4 * NCMB * 256 * 2);
    int*   combo  = (int*)  alloc((size_t)NN * 4);
    int*   eidx   = (int*)  alloc((size_t)NE * 4);
    int*   cnt    = (int*)  alloc((size_t)NB * 4);
    int*   off    = (int*)  alloc((size_t)(NB + 1) * 4);
    int*   cursor = (int*)  alloc((size_t)NB * 4);
    int*   bsum   = (int*)  alloc((size_t)NBLK * 4);
    int*   bbase  = (int*)  alloc((size_t)NBLK * 4);
    float* tab    = (float*)alloc((size_t)4 * 144 * 256 * 4);
    bf16*  W2t    = (bf16*) alloc((size_t)256 * 1024 * 2);
    float* pool   = (float*)alloc((size_t)NG * 256 * 4);
    float* gcnt   = (float*)alloc((size_t)NG * 4);
    (void)ws_size;

    // ---- CSR build
    zero_u32<<<(NB + 255) / 256, 256, 0, stream>>>((unsigned*)cnt, NB);
    count_edges<<<(NE + 255) / 256, 256, 0, stream>>>(ei, et, cnt);
    scan_block_sums<<<NBLK, 256, 0, stream>>>(cnt, bsum);
    scan_base<<<1, 64, 0, stream>>>(bsum, bbase, off);
    scan_write<<<NBLK, 256, 0, stream>>>(cnt, bbase, off, cursor);
    scatter_edges<<<(NE + 255) / 256, 256, 0, stream>>>(ei, et, cursor, eidx);

    // ---- weight/table prep
    tab_gemm<<<4 * 144, 256, 0, stream>>>(se, ce, pe, W1, root1, tab);
    node_combo<<<(NN + 255) / 256, 256, 0, stream>>>(s_idx, c_idx, p_idx, combo);
    comb_build<<<4 * NCMB, 256, 0, stream>>>(tab, b1, comb);
    conv_w2cat<<<(256 * 1024 + 255) / 256, 256, 0, stream>>>(W2, root2, W2t);

    // ---- layer 1: fully fused combo-table gather
    l1_fused<<<(NN + 3) / 4, 256, 0, stream>>>(off, eidx, combo, comb, h1);

    // ---- layer 2: aggregate-first (linear), then one concat GEMM with fused bias+relu
    agg_all<<<(NN + 3) / 4, 256, 0, stream>>>(off, eidx, h1, hagg);
    dim3 g2(2, (NN + 127) / 128);
    gemm_cat<<<g2, 256, 0, stream>>>(hagg, h1, W2t, b2, h2);

    // ---- pool + head
    zero_u32<<<(NG * 256 + NG + 255) / 256, 256, 0, stream>>>((unsigned*)pool, NG * 256 + NG);
    pool_rle<<<(NN + PN - 1) / PN, 256, 0, stream>>>(batch, h2, pool, gcnt);
    final_head<<<NG, 256, 0, stream>>>(pool, gcnt, lin_w, lin_b, out);
}

// Round 8
// 438.915 us; speedup vs baseline: 1.0616x; 1.0616x over previous
//
#include <hip/hip_runtime.h>
#include <hip/hip_bf16.h>

#define NN 50000          // nodes
#define NE 800000         // edges
#define NR 3              // relations
#define NG 500            // graphs
#define NB (NN * NR)      // (dst, rel) buckets = 150000
#define NCLS 10
#define NCMB 8192         // 8 shapes * 8 colors * 128 positions
#define CHUNK 2048        // scan elements per block
#define NBLK ((NB + CHUNK - 1) / CHUNK)   // 74

typedef __hip_bfloat16 bf16;
typedef __attribute__((ext_vector_type(8))) short short8;   // bf16x8 MFMA frag
typedef __attribute__((ext_vector_type(4))) float floatx4;  // MFMA accumulator

static __device__ __forceinline__ float b2f(bf16 x) { return __bfloat162float(x); }
static __device__ __forceinline__ bf16  f2b(float x) { return __float2bfloat16(x); }
static __device__ __forceinline__ float bs2f(short x) {
    return __bfloat162float(*reinterpret_cast<const bf16*>(&x));
}
static __device__ __forceinline__ short f2bs(float x) {
    bf16 b = __float2bfloat16(x);
    return *reinterpret_cast<const short*>(&b);
}

// ---------------- zero words (graph-capture-safe)
__global__ __launch_bounds__(256) void zero_u32(unsigned* __restrict__ p, long n) {
    long i = (long)blockIdx.x * 256 + threadIdx.x;
    if (i < n) p[i] = 0u;
}

// ---------------- per-(dst,rel) edge counts
__global__ __launch_bounds__(256) void count_edges(const int* __restrict__ ei,
                                                   const int* __restrict__ et,
                                                   int* __restrict__ cnt) {
    int e = blockIdx.x * 256 + threadIdx.x;
    if (e >= NE) return;
    atomicAdd(&cnt[ei[NE + e] * NR + et[e]], 1);
}

// ---------------- counting-sort scan, phase A: per-block (2048-elem) totals
__global__ __launch_bounds__(256) void scan_block_sums(const int* __restrict__ cnt,
                                                       int* __restrict__ bsum) {
    __shared__ int sm[256];
    int b = blockIdx.x, t = threadIdx.x;
    int base = b * CHUNK + t * 8, s = 0;
#pragma unroll
    for (int j = 0; j < 8; ++j) { int i = base + j; if (i < NB) s += cnt[i]; }
    sm[t] = s; __syncthreads();
    for (int st = 128; st; st >>= 1) { if (t < st) sm[t] += sm[t + st]; __syncthreads(); }
    if (!t) bsum[b] = sm[0];
}

// ---------------- phase B: exclusive scan of the 74 block sums
__global__ void scan_base(const int* __restrict__ bsum, int* __restrict__ bbase,
                          int* __restrict__ off) {
    if (threadIdx.x == 0 && blockIdx.x == 0) {
        int run = 0;
        for (int i = 0; i < NBLK; ++i) { bbase[i] = run; run += bsum[i]; }
        off[NB] = run;   // == NE
    }
}

// ---------------- phase C: in-block exclusive scan + base -> off[], cursor[]
__global__ __launch_bounds__(256) void scan_write(const int* __restrict__ cnt,
                                                  const int* __restrict__ bbase,
                                                  int* __restrict__ off,
                                                  int* __restrict__ cursor) {
    int b = blockIdx.x, t = threadIdx.x;
    int base = b * CHUNK + t * 8;
    int v[8], ts = 0;
#pragma unroll
    for (int j = 0; j < 8; ++j) { int i = base + j; v[j] = (i < NB) ? cnt[i] : 0; ts += v[j]; }
    int lane = t & 63, wv = t >> 6;
    int incl = ts;
    for (int d = 1; d < 64; d <<= 1) {
        int o = __shfl_up(incl, d, 64);
        if (lane >= d) incl += o;
    }
    __shared__ int wsum[4];
    if (lane == 63) wsum[wv] = incl;
    __syncthreads();
    int wbase = 0;
    for (int w = 0; w < wv; ++w) wbase += wsum[w];
    int run = bbase[b] + wbase + incl - ts;
#pragma unroll
    for (int j = 0; j < 8; ++j) {
        int i = base + j;
        if (i < NB) { off[i] = run; cursor[i] = run; }
        run += v[j];
    }
}

// ---------------- bucket-sort edge src indices (CSR payload)
__global__ __launch_bounds__(256) void scatter_edges(const int* __restrict__ ei,
                                                     const int* __restrict__ et,
                                                     int* __restrict__ cursor,
                                                     int* __restrict__ eidx) {
    int e = blockIdx.x * 256 + threadIdx.x;
    if (e >= NE) return;
    int b = ei[NE + e] * NR + et[e];
    int pos = atomicAdd(&cursor[b], 1);
    eidx[pos] = ei[e];
}

// ---------------- layer-1 tables: tab[r][row][n], r in 0..3 (3 rels + root)
__global__ __launch_bounds__(256) void tab_gemm(const float* __restrict__ se,
                                                const float* __restrict__ ce,
                                                const float* __restrict__ pe,
                                                const float* __restrict__ W1,
                                                const float* __restrict__ root1,
                                                float* __restrict__ tab) {
    int bid = blockIdx.x;              // 4*144 blocks
    int r = bid / 144, row = bid % 144;
    int t = threadIdx.x;               // output column 0..255
    const float* A; int segk;
    if (row < 8)       { A = se + row * 128;        segk = 0; }
    else if (row < 16) { A = ce + (row - 8) * 128;  segk = 128; }
    else               { A = pe + (row - 16) * 128; segk = 256; }
    const float* W = (r < 3) ? (W1 + (size_t)r * 384 * 256) : root1;
    float acc = 0.f;
    for (int k = 0; k < 128; ++k)
        acc += A[k] * W[(size_t)(segk + k) * 256 + t];
    tab[((size_t)r * 144 + row) * 256 + t] = acc;
}

// ---------------- node combo ids: combo[n] = s*1024 + c*128 + p
__global__ __launch_bounds__(256) void node_combo(const int* __restrict__ s,
                                                  const int* __restrict__ c,
                                                  const int* __restrict__ p,
                                                  int* __restrict__ combo) {
    int n = blockIdx.x * 256 + threadIdx.x;
    if (n < NN) combo[n] = (s[n] << 10) | (c[n] << 7) | p[n];
}

// ---------------- comb[r][cmb][d] = tab[r][s]+tab[r][8+c]+tab[r][16+p] (+b1 for r=3), bf16
__global__ __launch_bounds__(256) void comb_build(const float* __restrict__ tab,
                                                  const float* __restrict__ b1,
                                                  bf16* __restrict__ comb) {
    int bid = blockIdx.x;              // 4*8192
    int r = bid >> 13, cmb = bid & (NCMB - 1);
    int d = threadIdx.x;
    int si = cmb >> 10, ci = (cmb >> 7) & 7, pi = cmb & 127;
    const float* tr = tab + (size_t)r * 144 * 256;
    float v = tr[si * 256 + d] + tr[(8 + ci) * 256 + d] + tr[(16 + pi) * 256 + d];
    if (r == 3) v += b1[d];
    comb[(size_t)bid * 256 + d] = f2b(v);
}

// ---------------- fused layer 1: 4 waves/block, 1 wave/dst.
// Lane-split gather: half = lane>>5 handles even/odd rows; 32 lanes x short8 = 512 B row.
// 2x unrolled -> 4 independent row loads in flight per wave.
__global__ __launch_bounds__(256) void l1_fused(const int* __restrict__ off,
                                                const int* __restrict__ eidx,
                                                const int* __restrict__ combo,
                                                const bf16* __restrict__ comb,
                                                bf16* __restrict__ h1) {
    int wave = threadIdx.x >> 6, lane = threadIdx.x & 63;
    int dst = blockIdx.x * 4 + wave;
    if (dst >= NN) return;
    int half = lane >> 5, li8 = (lane & 31) * 8;
    float acc[8];
    if (half == 0) {   // root slice (b1 pre-folded); only half0's acc is used
        int cmbD = combo[dst];
        short8 rv = *(const short8*)(comb + ((size_t)(3 * NCMB) + cmbD) * 256 + li8);
#pragma unroll
        for (int i = 0; i < 8; ++i) acc[i] = bs2f(rv[i]);
    } else {
#pragma unroll
        for (int i = 0; i < 8; ++i) acc[i] = 0.f;
    }
    for (int r = 0; r < NR; ++r) {
        int lo = off[dst * NR + r], hi = off[dst * NR + r + 1];
        if (hi <= lo) continue;                 // empty bucket contributes 0 (matches ref)
        const bf16* cr = comb + (size_t)r * NCMB * 256;
        float s[8] = {};
        int j = lo;
        for (; j + 4 <= hi; j += 4) {           // 2 edges/half -> 4 rows in flight
            int e0 = eidx[j + half], e1 = eidx[j + 2 + half];
            int c0 = combo[e0], c1 = combo[e1];
            short8 v0 = *(const short8*)(cr + (size_t)c0 * 256 + li8);
            short8 v1 = *(const short8*)(cr + (size_t)c1 * 256 + li8);
#pragma unroll
            for (int i = 0; i < 8; ++i) s[i] += bs2f(v0[i]) + bs2f(v1[i]);
        }
        for (; j + 2 <= hi; j += 2) {
            int e0 = eidx[j + half];
            short8 v0 = *(const short8*)(cr + (size_t)combo[e0] * 256 + li8);
#pragma unroll
            for (int i = 0; i < 8; ++i) s[i] += bs2f(v0[i]);
        }
        if (j < hi && half == 0) {              // odd remainder
            short8 v0 = *(const short8*)(cr + (size_t)combo[eidx[j]] * 256 + li8);
#pragma unroll
            for (int i = 0; i < 8; ++i) s[i] += bs2f(v0[i]);
        }
        float inv = 1.0f / (float)(hi - lo);
#pragma unroll
        for (int i = 0; i < 8; ++i) {
            float tot = s[i] + __shfl_xor(s[i], 32);
            if (half == 0) acc[i] += tot * inv;
        }
    }
    if (half == 0) {
        short8 o;
#pragma unroll
        for (int i = 0; i < 8; ++i) o[i] = f2bs(fmaxf(acc[i], 0.f));
        *(short8*)(h1 + (size_t)dst * 256 + li8) = o;
    }
}

// ---------------- per-relation mean aggregation of h1 (aggregate BEFORE transform):
// hagg[dst][r*256+d] = mean_{src in bucket(dst,r)} h1[src][d]   (0 if empty)
// Same lane-split gather structure as l1_fused.
__global__ __launch_bounds__(256) void agg_all(const int* __restrict__ off,
                                               const int* __restrict__ eidx,
                                               const bf16* __restrict__ h1,
                                               bf16* __restrict__ hagg) {
    int wave = threadIdx.x >> 6, lane = threadIdx.x & 63;
    int dst = blockIdx.x * 4 + wave;
    if (dst >= NN) return;
    int half = lane >> 5, li8 = (lane & 31) * 8;
    for (int r = 0; r < NR; ++r) {
        int lo = off[dst * NR + r], hi = off[dst * NR + r + 1];
        float s[8] = {};
        int j = lo;
        for (; j + 4 <= hi; j += 4) {
            int e0 = eidx[j + half], e1 = eidx[j + 2 + half];
            short8 v0 = *(const short8*)(h1 + (size_t)e0 * 256 + li8);
            short8 v1 = *(const short8*)(h1 + (size_t)e1 * 256 + li8);
#pragma unroll
            for (int i = 0; i < 8; ++i) s[i] += bs2f(v0[i]) + bs2f(v1[i]);
        }
        for (; j + 2 <= hi; j += 2) {
            int e0 = eidx[j + half];
            short8 v0 = *(const short8*)(h1 + (size_t)e0 * 256 + li8);
#pragma unroll
            for (int i = 0; i < 8; ++i) s[i] += bs2f(v0[i]);
        }
        if (j < hi && half == 0) {
            short8 v0 = *(const short8*)(h1 + (size_t)eidx[j] * 256 + li8);
#pragma unroll
            for (int i = 0; i < 8; ++i) s[i] += bs2f(v0[i]);
        }
        float inv = (hi > lo) ? 1.0f / (float)(hi - lo) : 0.f;
        short8 o;
#pragma unroll
        for (int i = 0; i < 8; ++i) {
            float tot = s[i] + __shfl_xor(s[i], 32);
            o[i] = f2bs(tot * inv);
        }
        if (half == 0)
            *(short8*)(hagg + (size_t)dst * 768 + r * 256 + li8) = o;
    }
}

// ---------------- W2cat -> bf16, transposed on K: Wt[n][k], k = [W2_0;W2_1;W2_2;root2]
__global__ __launch_bounds__(256) void conv_w2cat(const float* __restrict__ W2,
                                                  const float* __restrict__ root2,
                                                  bf16* __restrict__ Wt) {
    int idx = blockIdx.x * 256 + threadIdx.x;   // 256*1024
    if (idx >= 256 * 1024) return;
    int n = idx >> 10, k = idx & 1023;
    float v = (k < 768) ? W2[((size_t)(k >> 8) * 256 + (k & 255)) * 256 + n]
                        : root2[(size_t)(k - 768) * 256 + n];
    Wt[idx] = f2b(v);
}

// ---------------- concat MFMA GEMM + fused epilogue, v2 (latency-oriented):
// h2[M][256] = relu( [hagg | h1] (M x 1024) @ Wt^T + b2 )
// 64x128 tile, grid (2, 782) -> ~6 blocks/CU; LDS double-buffer with register
// prefetch of chunk k+1 issued before the MFMAs of chunk k; ONE barrier per step.
__global__ __launch_bounds__(256) void gemm_cat(const bf16* __restrict__ hagg,
                                                const bf16* __restrict__ h1,
                                                const bf16* __restrict__ Wt,
                                                const float* __restrict__ bias,
                                                bf16* __restrict__ h2) {
    __shared__ short As[2][64 * 40];    // 10.2 KB  (row stride 40 shorts = 80 B)
    __shared__ short Bs[2][128 * 40];   // 20.5 KB
    const int t = threadIdx.x;
    const int wave = t >> 6, lane = t & 63;
    const int quad = lane >> 4, l16 = lane & 15;
    const int mq = (wave & 1) * 32;     // wave's 32-row m-range
    const int nq = (wave >> 1) * 64;    // wave's 64-col n-range
    const int row0 = blockIdx.y * 64, col0 = blockIdx.x * 128;
    const int sr = t >> 2;              // staging row 0..63
    const int sp = (t & 3) * 8;         // staging k-offset {0,8,16,24}
    const int gmA = row0 + sr;

    auto loadA = [&](int k0) -> short8 {
        short8 v = {};
        int k = k0 + sp;
        if (gmA < NN)
            v = (k < 768) ? *(const short8*)(hagg + (size_t)gmA * 768 + k)
                          : *(const short8*)(h1 + (size_t)gmA * 256 + (k - 768));
        return v;
    };
    auto loadB = [&](int k0, int rlocal) -> short8 {
        return *(const short8*)(Wt + (size_t)(col0 + rlocal) * 1024 + k0 + sp);
    };

    floatx4 acc[2][4] = {};

    // prologue: stage chunk 0 into buffer 0
    {
        short8 a = loadA(0), b0 = loadB(0, sr), b1 = loadB(0, sr + 64);
        *(short8*)&As[0][sr * 40 + sp] = a;
        *(short8*)&Bs[0][sr * 40 + sp] = b0;
        *(short8*)&Bs[0][(sr + 64) * 40 + sp] = b1;
    }
    __syncthreads();

    for (int i = 0; i < 32; ++i) {
        const int cur = i & 1;
        short8 a_n, b0_n, b1_n;
        if (i + 1 < 32) {               // issue prefetch loads first (latency overlap)
            int k0 = (i + 1) * 32;
            a_n = loadA(k0); b0_n = loadB(k0, sr); b1_n = loadB(k0, sr + 64);
        }
        short8 af[2], bfr[4];
#pragma unroll
        for (int mi = 0; mi < 2; ++mi)
            af[mi] = *(const short8*)&As[cur][(mq + mi * 16 + l16) * 40 + quad * 8];
#pragma unroll
        for (int ni = 0; ni < 4; ++ni)
            bfr[ni] = *(const short8*)&Bs[cur][(nq + ni * 16 + l16) * 40 + quad * 8];
#pragma unroll
        for (int mi = 0; mi < 2; ++mi)
#pragma unroll
            for (int ni = 0; ni < 4; ++ni)
                acc[mi][ni] = __builtin_amdgcn_mfma_f32_16x16x32_bf16(
                    af[mi], bfr[ni], acc[mi][ni], 0, 0, 0);
        if (i + 1 < 32) {
            int alt = 1 - cur;          // last read at step i-1; barrier of i-1 passed
            *(short8*)&As[alt][sr * 40 + sp] = a_n;
            *(short8*)&Bs[alt][sr * 40 + sp] = b0_n;
            *(short8*)&Bs[alt][(sr + 64) * 40 + sp] = b1_n;
        }
        __syncthreads();
    }

    // C/D layout: col = lane&15, row = quad*4 + reg   [m89/m91-verified]
#pragma unroll
    for (int mi = 0; mi < 2; ++mi) {
#pragma unroll
        for (int ni = 0; ni < 4; ++ni) {
            int n = col0 + nq + ni * 16 + l16;
#pragma unroll
            for (int ii = 0; ii < 4; ++ii) {
                int gm = row0 + mq + mi * 16 + quad * 4 + ii;
                if (gm < NN) {
                    float v = acc[mi][ni][ii] + bias[n];
                    h2[(size_t)gm * 256 + n] = f2b(fmaxf(v, 0.f));
                }
            }
        }
    }
}

// ---------------- pooling via run-length reduction (batch is SORTED)
#define PN 64
__global__ __launch_bounds__(256) void pool_rle(const int* __restrict__ batch,
                                                const bf16* __restrict__ H,
                                                float* __restrict__ pool,
                                                float* __restrict__ gcnt) {
    int t = threadIdx.x;               // feature dim
    int n0 = blockIdx.x * PN;
    int nend = n0 + PN; if (nend > NN) nend = NN;
    int curg = batch[n0];
    float acc = 0.f, cnt = 0.f;
    for (int n = n0; n < nend; ++n) {
        int g = batch[n];              // wave-uniform
        if (g != curg) {
            atomicAdd(&pool[(size_t)curg * 256 + t], acc);
            if (t == 0) atomicAdd(&gcnt[curg], cnt);
            acc = 0.f; cnt = 0.f; curg = g;
        }
        acc += b2f(H[(size_t)n * 256 + t]);
        cnt += 1.f;
    }
    atomicAdd(&pool[(size_t)curg * 256 + t], acc);
    if (t == 0) atomicAdd(&gcnt[curg], cnt);
}

// ---------------- head: out[g][c] = (pool[g]/cnt[g]) @ lin_w + lin_b  (f32 out)
__global__ __launch_bounds__(256) void final_head(const float* __restrict__ pool,
                                                  const float* __restrict__ gcnt,
                                                  const float* __restrict__ lin_w,
                                                  const float* __restrict__ lin_b,
                                                  float* __restrict__ out) {
    __shared__ float sm[256];
    int g = blockIdx.x, t = threadIdx.x;
    float inv = 1.0f / fmaxf(gcnt[g], 1.0f);
    sm[t] = pool[(size_t)g * 256 + t] * inv;
    __syncthreads();
    if (t < NCLS) {
        float s = lin_b[t];
        for (int d = 0; d < 256; ++d) s += sm[d] * lin_w[d * NCLS + t];
        out[g * NCLS + t] = s;
    }
}

extern "C" void kernel_launch(void* const* d_in, const int* in_sizes, int n_in,
                              void* d_out, int out_size, void* d_ws, size_t ws_size,
                              hipStream_t stream) {
    const int*   s_idx = (const int*)d_in[0];
    const int*   c_idx = (const int*)d_in[1];
    const int*   p_idx = (const int*)d_in[2];
    const int*   ei    = (const int*)d_in[3];   // (2, NE)
    const int*   et    = (const int*)d_in[4];
    const int*   batch = (const int*)d_in[5];
    const float* se    = (const float*)d_in[6];
    const float* ce    = (const float*)d_in[7];
    const float* pe    = (const float*)d_in[8];
    const float* W1    = (const float*)d_in[9];   // (3, 384, 256)
    const float* root1 = (const float*)d_in[10];  // (384, 256)
    const float* b1    = (const float*)d_in[11];
    const float* W2    = (const float*)d_in[12];  // (3, 256, 256)
    const float* root2 = (const float*)d_in[13];  // (256, 256)
    const float* b2    = (const float*)d_in[14];
    const float* lin_w = (const float*)d_in[15];
    const float* lin_b = (const float*)d_in[16];
    float* out = (float*)d_out;

    // ---- workspace carve-up (~172 MB; ws_size >= 190 MB confirmed in round 6)
    char* w = (char*)d_ws;
    size_t o = 0;
    auto alloc = [&](size_t bytes) -> void* {
        o = (o + 15) & ~(size_t)15;
        void* ptr = w + o;
        o += bytes;
        return ptr;
    };
    bf16*  hagg   = (bf16*) alloc((size_t)NN * 768 * 2);   // 76.8 MB
    bf16*  h1     = (bf16*) alloc((size_t)NN * 256 * 2);
    bf16*  h2     = (bf16*) alloc((size_t)NN * 256 * 2);
    bf16*  comb   = (bf16*) alloc((size_t)4 * NCMB * 256 * 2);
    int*   combo  = (int*)  alloc((size_t)NN * 4);
    int*   eidx   = (int*)  alloc((size_t)NE * 4);
    int*   cnt    = (int*)  alloc((size_t)NB * 4);
    int*   off    = (int*)  alloc((size_t)(NB + 1) * 4);
    int*   cursor = (int*)  alloc((size_t)NB * 4);
    int*   bsum   = (int*)  alloc((size_t)NBLK * 4);
    int*   bbase  = (int*)  alloc((size_t)NBLK * 4);
    float* tab    = (float*)alloc((size_t)4 * 144 * 256 * 4);
    bf16*  W2t    = (bf16*) alloc((size_t)256 * 1024 * 2);
    float* pool   = (float*)alloc((size_t)NG * 256 * 4);
    float* gcnt   = (float*)alloc((size_t)NG * 4);
    (void)ws_size;

    // ---- CSR build
    zero_u32<<<(NB + 255) / 256, 256, 0, stream>>>((unsigned*)cnt, NB);
    count_edges<<<(NE + 255) / 256, 256, 0, stream>>>(ei, et, cnt);
    scan_block_sums<<<NBLK, 256, 0, stream>>>(cnt, bsum);
    scan_base<<<1, 64, 0, stream>>>(bsum, bbase, off);
    scan_write<<<NBLK, 256, 0, stream>>>(cnt, bbase, off, cursor);
    scatter_edges<<<(NE + 255) / 256, 256, 0, stream>>>(ei, et, cursor, eidx);

    // ---- weight/table prep
    tab_gemm<<<4 * 144, 256, 0, stream>>>(se, ce, pe, W1, root1, tab);
    node_combo<<<(NN + 255) / 256, 256, 0, stream>>>(s_idx, c_idx, p_idx, combo);
    comb_build<<<4 * NCMB, 256, 0, stream>>>(tab, b1, comb);
    conv_w2cat<<<(256 * 1024 + 255) / 256, 256, 0, stream>>>(W2, root2, W2t);

    // ---- layer 1: fully fused combo-table gather
    l1_fused<<<(NN + 3) / 4, 256, 0, stream>>>(off, eidx, combo, comb, h1);

    // ---- layer 2: aggregate-first, then one concat GEMM with fused bias+relu
    agg_all<<<(NN + 3) / 4, 256, 0, stream>>>(off, eidx, h1, hagg);
    dim3 g2(2, (NN + 63) / 64);
    gemm_cat<<<g2, 256, 0, stream>>>(hagg, h1, W2t, b2, h2);

    // ---- pool + head
    zero_u32<<<(NG * 256 + NG + 255) / 256, 256, 0, stream>>>((unsigned*)pool, NG * 256 + NG);
    pool_rle<<<(NN + PN - 1) / PN, 256, 0, stream>>>(batch, h2, pool, gcnt);
    final_head<<<NG, 256, 0, stream>>>(pool, gcnt, lin_w, lin_b, out);
}